// Round 4
// baseline (128.566 us; speedup 1.0000x reference)
//
#include <hip/hip_runtime.h>
#include <cstdint>

#define N_PTS 65536
#define DIM   1024
#define K_CL  256
#define BN    256
#define BK    32
#define NT    (DIM / BK)   // 32 k-tiles
#define THREADS 512

typedef __bf16 bf16_t;
typedef bf16_t bf16x8 __attribute__((ext_vector_type(8)));
typedef float  f32x4  __attribute__((ext_vector_type(4)));

union U16x8 { uint4 u4; bf16x8 bf; ushort us[8]; };

__device__ __forceinline__ ushort f2bf_rne(float f) {
    uint32_t u = __float_as_uint(f);
    uint32_t r = (u + 0x7FFFu + ((u >> 16) & 1u)) >> 16;
    return (ushort)r;
}
__device__ __forceinline__ float bf2f(ushort b) {
    return __uint_as_float(((uint32_t)b) << 16);
}

__device__ __forceinline__ void gll16(const void* g, void* l) {
    __builtin_amdgcn_global_load_lds(
        (const __attribute__((address_space(1))) void*)g,
        (__attribute__((address_space(3))) void*)l, 16, 0, 0);
}

#define BAR()   __builtin_amdgcn_s_barrier()
#define SCHB()  __builtin_amdgcn_sched_barrier(0)
#define LGKM0() do { asm volatile("s_waitcnt lgkmcnt(0)" ::: "memory"); \
                     __builtin_amdgcn_sched_barrier(0); } while (0)
#define VMCNT(N) do { asm volatile("s_waitcnt vmcnt(" #N ")" ::: "memory"); \
                      __builtin_amdgcn_sched_barrier(0); } while (0)
#define MFMA(ACC, A, B) (ACC) = __builtin_amdgcn_mfma_f32_16x16x32_bf16((A).bf, (B).bf, (ACC), 0, 0, 0)

// ---------------------------------------------------------------------------
// Kernel 0: centroids fp32 -> pre-swizzled bf16 hi/lo tile images + c_sq.
// ws layout per split: [NT tiles][256 rows][4 groups][8 bf16]; physical group
// slot gp holds d-group (gp ^ s), s = (row>>1)&3, so a LINEAR LDS copy of a
// tile gives bank-conflict-free swizzled reads (read slot g^s for d-group g).
// ---------------------------------------------------------------------------
__global__ __launch_bounds__(128) void km_prep(const float* __restrict__ cent,
                                               ushort* __restrict__ Ahi,
                                               ushort* __restrict__ Alo,
                                               float* __restrict__ csq) {
    const int r  = blockIdx.x;        // centroid row 0..255
    const int j  = threadIdx.x;       // 0..127
    const int kt = j >> 2;
    const int gp = j & 3;
    const int s  = (r >> 1) & 3;
    const int d0 = kt * BK + ((gp ^ s) << 3);

    const float* src = cent + r * DIM + d0;
    float4 a = *(const float4*)src;
    float4 b = *(const float4*)(src + 4);
    float v[8] = {a.x, a.y, a.z, a.w, b.x, b.y, b.z, b.w};

    U16x8 hi, lo;
    float ss = 0.f;
#pragma unroll
    for (int i = 0; i < 8; ++i) {
        float f = v[i];
        ss += f * f;
        ushort h = f2bf_rne(f);
        hi.us[i] = h;
        lo.us[i] = f2bf_rne(f - bf2f(h));
    }
    *(uint4*)(Ahi + kt * (K_CL * BK) + r * BK + gp * 8) = hi.u4;
    *(uint4*)(Alo + kt * (K_CL * BK) + r * BK + gp * 8) = lo.u4;

#pragma unroll
    for (int off = 1; off < 64; off <<= 1) ss += __shfl_xor(ss, off);
    __shared__ float ws2[2];
    if ((j & 63) == 0) ws2[j >> 6] = ss;
    __syncthreads();
    if (j == 0) csq[r] = ws2[0] + ws2[1];
}

// ---------------------------------------------------------------------------
// Kernel 1: fused distances + argmin + loss partial.
// Block = 512 thr (8 waves), tile 256 (all K) x 256 cols; wave = 64 x 128.
// 4-phase K-step, phases organized by PRODUCT CLASS so every phase has <=8
// LDS reads and the convert/ds_write tax is split across the two 32-MFMA
// phases.  Counted vmcnt ladder: b-loads -> VMCNT(6)/(4); A-glls -> VMCNT(0)
// issued >=2 phases earlier.  Split-bf16: hh + hl + lh.
// ---------------------------------------------------------------------------
__global__ __launch_bounds__(THREADS, 2) void km_main(
    const float* __restrict__ x,
    const ushort* __restrict__ Ahi, const ushort* __restrict__ Alo,
    const float* __restrict__ csq,
    float* __restrict__ out_dist, float* __restrict__ out_assign,
    float* __restrict__ partials) {

    __shared__ __align__(16) ushort sAhi[2][K_CL * BK];   // 32 KB
    __shared__ __align__(16) ushort sAlo[2][K_CL * BK];   // 32 KB
    __shared__ __align__(16) ushort sBhi[2][BN * BK];     // 32 KB
    __shared__ __align__(16) ushort sBlo[2][BN * BK];     // 32 KB
    __shared__ __align__(16) float  sCsq[K_CL];
    __shared__ __align__(16) float  sXsq[BN];
    __shared__ float sRedV[4 * BN];
    __shared__ int   sRedI[4 * BN];
    __shared__ float sWsum[8];

    const int tid  = threadIdx.x;
    const int blk  = blockIdx.x;
    const int lane = tid & 63;
    const int w    = tid >> 6;
    const int wr   = w >> 1;      // 0..3 row group (64 rows)
    const int wc   = w & 1;       // 0..1 col group (128 cols)
    const int l15  = lane & 15;
    const int l4   = lane >> 4;   // 0..3

    if (tid < K_CL) sCsq[tid] = csq[tid];

    // B staging: 2 threads per column, 16 d-elements each.
    const int bcol  = tid >> 1;                 // 0..255
    const int bhalf = tid & 1;                  // d-half: 0 -> d0..15, 1 -> d16..31
    const int bs    = (bcol >> 1) & 3;          // swizzle key
    const int bOff0 = bcol * BK + ((((bhalf << 1) | 0) ^ bs) << 3);
    const int bOff1 = bcol * BK + ((((bhalf << 1) | 1) ^ bs) << 3);
    const float* xsrc = x + (size_t)(blk * BN + bcol) * DIM + bhalf * 16;

    float xs_acc = 0.f;

    auto stageA_hi = [&](int kt, int buf) {
        const char* ph = (const char*)Ahi + kt * 16384 + tid * 16;
        char* dh = (char*)&sAhi[buf][0] + tid * 16;
        gll16(ph, dh);
        gll16(ph + 8192, dh + 8192);
    };
    auto stageA_lo = [&](int kt, int buf) {
        const char* pl = (const char*)Alo + kt * 16384 + tid * 16;
        char* dl = (char*)&sAlo[buf][0] + tid * 16;
        gll16(pl, dl);
        gll16(pl + 8192, dl + 8192);
    };
    // one half (8 elems = one b128 row pair) of the B convert+write
    auto writeB_half = [&](int buf, float4 u, float4 v, int half) {
        float f[8] = {u.x, u.y, u.z, u.w, v.x, v.y, v.z, v.w};
        U16x8 h, l;
#pragma unroll
        for (int i = 0; i < 8; ++i) {
            float a = f[i];
            xs_acc = fmaf(a, a, xs_acc);
            bf16_t hb = (bf16_t)a;
            h.bf[i] = hb;
            l.bf[i] = (bf16_t)(a - (float)hb);
        }
        const int off = half ? bOff1 : bOff0;
        *(uint4*)&sBhi[buf][off] = h.u4;
        *(uint4*)&sBlo[buf][off] = l.u4;
    };

    // fragment LDS offsets (ushort units), swizzle folded in
    int aOff[4], bOff[8];
#pragma unroll
    for (int f = 0; f < 4; ++f) {
        int row  = wr * 64 + f * 16 + l15;
        aOff[f]  = row * BK + ((l4 ^ ((row >> 1) & 3)) << 3);
    }
#pragma unroll
    for (int f = 0; f < 8; ++f) {
        int col  = wc * 128 + f * 16 + l15;
        bOff[f]  = col * BK + ((l4 ^ ((col >> 1) & 3)) << 3);
    }

    // prologue: stage tile 0
    float4 b0, b1, b2, b3;
    stageA_hi(0, 0);
    stageA_lo(0, 0);
    b0 = *(const float4*)(xsrc);
    b1 = *(const float4*)(xsrc + 4);
    b2 = *(const float4*)(xsrc + 8);
    b3 = *(const float4*)(xsrc + 12);
    writeB_half(0, b0, b1, 0);
    writeB_half(0, b2, b3, 1);
    __syncthreads();

    f32x4 acc[4][8];
#pragma unroll
    for (int i = 0; i < 4; ++i)
#pragma unroll
        for (int q = 0; q < 8; ++q) acc[i][q] = (f32x4){0.f, 0.f, 0.f, 0.f};

    for (int kt = 0; kt < NT; ++kt) {
        const int  cur = kt & 1, nxt = cur ^ 1;
        const bool pf  = (kt + 1 < NT);

        U16x8 ah[4], al[4], bh[8], bl[8];

        // ---- Phase 0: b-loads(kt+1), reads {ah x4, bh01, bl01}, gll A-hi ----
        if (pf) {
            const float* p = xsrc + (kt + 1) * BK;
            b0 = *(const float4*)p;
            b1 = *(const float4*)(p + 4);
            b2 = *(const float4*)(p + 8);
            b3 = *(const float4*)(p + 12);
        }
#pragma unroll
        for (int f = 0; f < 4; ++f) ah[f].u4 = *(const uint4*)&sAhi[cur][aOff[f]];
        bh[0].u4 = *(const uint4*)&sBhi[cur][bOff[0]];
        bh[1].u4 = *(const uint4*)&sBhi[cur][bOff[1]];
        bl[0].u4 = *(const uint4*)&sBlo[cur][bOff[0]];
        bl[1].u4 = *(const uint4*)&sBlo[cur][bOff[1]];
        if (pf) stageA_hi(kt + 1, nxt);
        SCHB();
        BAR();
        LGKM0();
        __builtin_amdgcn_s_setprio(1);
#pragma unroll
        for (int fj = 0; fj < 2; ++fj)
#pragma unroll
            for (int fi = 0; fi < 4; ++fi) MFMA(acc[fi][fj], ah[fi], bh[fj]);   // hh01
#pragma unroll
        for (int fj = 0; fj < 2; ++fj)
#pragma unroll
            for (int fi = 0; fi < 4; ++fi) MFMA(acc[fi][fj], ah[fi], bl[fj]);   // hl01
        __builtin_amdgcn_s_setprio(0);
        BAR();

        // ---- Phase 1: reads {al x4, bh23, bl23}, gll A-lo ----
#pragma unroll
        for (int f = 0; f < 4; ++f) al[f].u4 = *(const uint4*)&sAlo[cur][aOff[f]];
        bh[2].u4 = *(const uint4*)&sBhi[cur][bOff[2]];
        bh[3].u4 = *(const uint4*)&sBhi[cur][bOff[3]];
        bl[2].u4 = *(const uint4*)&sBlo[cur][bOff[2]];
        bl[3].u4 = *(const uint4*)&sBlo[cur][bOff[3]];
        if (pf) stageA_lo(kt + 1, nxt);
        SCHB();
        BAR();
        LGKM0();
        __builtin_amdgcn_s_setprio(1);
#pragma unroll
        for (int fj = 2; fj < 4; ++fj)
#pragma unroll
            for (int fi = 0; fi < 4; ++fi) MFMA(acc[fi][fj], ah[fi], bh[fj]);   // hh23
#pragma unroll
        for (int fj = 2; fj < 4; ++fj)
#pragma unroll
            for (int fi = 0; fi < 4; ++fi) MFMA(acc[fi][fj], ah[fi], bl[fj]);   // hl23
        __builtin_amdgcn_s_setprio(0);
        BAR();

        // ---- Phase 2: reads {bh4..7, bl4..7}, convert+write B half0 ----
#pragma unroll
        for (int f = 4; f < 8; ++f) {
            bh[f].u4 = *(const uint4*)&sBhi[cur][bOff[f]];
            bl[f].u4 = *(const uint4*)&sBlo[cur][bOff[f]];
        }
        if (pf) {
            VMCNT(6);                       // b0,b1 landed (4 glls + b2,b3 in flight)
            writeB_half(nxt, b0, b1, 0);
        }
        SCHB();
        BAR();
        LGKM0();
        __builtin_amdgcn_s_setprio(1);
#pragma unroll
        for (int fj = 4; fj < 8; ++fj)
#pragma unroll
            for (int fi = 0; fi < 4; ++fi) MFMA(acc[fi][fj], ah[fi], bh[fj]);   // hh4567
#pragma unroll
        for (int fj = 4; fj < 8; ++fj)
#pragma unroll
            for (int fi = 0; fi < 4; ++fi) MFMA(acc[fi][fj], ah[fi], bl[fj]);   // hl4567
        __builtin_amdgcn_s_setprio(0);
        BAR();

        // ---- Phase 3: zero reads; convert+write B half1; all 32 lh MFMA ----
        if (pf) {
            VMCNT(4);                       // b2,b3 landed (4 glls in flight)
            writeB_half(nxt, b2, b3, 1);
        }
        SCHB();
        BAR();
        LGKM0();                            // own ds_writes
        __builtin_amdgcn_s_setprio(1);
#pragma unroll
        for (int fj = 0; fj < 8; ++fj)
#pragma unroll
            for (int fi = 0; fi < 4; ++fi) MFMA(acc[fi][fj], al[fi], bh[fj]);   // lh all
        __builtin_amdgcn_s_setprio(0);
        if (pf) VMCNT(0);                   // A-glls (issued P0/P1) landed
        BAR();
    }

    // x_sq: 2 threads per column
    {
        float v = xs_acc;
        v += __shfl_xor(v, 1);
        if (bhalf == 0) sXsq[bcol] = v;
    }
    __syncthreads();

    // epilogue: distances, argmin, loss
    const int colBase = wc * 128;
    float xs[8];
    f32x4 cs[4];
#pragma unroll
    for (int f = 0; f < 8; ++f) xs[f] = sXsq[colBase + f * 16 + l15];
#pragma unroll
    for (int f = 0; f < 4; ++f) cs[f] = *(const f32x4*)&sCsq[wr * 64 + f * 16 + l4 * 4];

    float lsum = 0.f;
    float bestv[8];
    int   bestr[8];
#pragma unroll
    for (int f = 0; f < 8; ++f) { bestv[f] = 3.4e38f; bestr[f] = 0; }

#pragma unroll
    for (int fi = 0; fi < 4; ++fi) {
        const int rowB = wr * 64 + fi * 16 + l4 * 4;
#pragma unroll
        for (int fj = 0; fj < 8; ++fj) {
            const int col = blk * BN + colBase + fj * 16 + l15;
            float* outp = out_dist + (size_t)rowB * N_PTS + col;
#pragma unroll
            for (int j = 0; j < 4; ++j) {
                float d = cs[fi][j] + xs[fj] - 2.0f * acc[fi][fj][j];
                outp[(size_t)j * N_PTS] = d;
                lsum += d;
                int r = rowB + j;
                if (d < bestv[fj]) { bestv[fj] = d; bestr[fj] = r; }
            }
        }
    }

    // wave argmin over the wave's 64 rows (lanes l, l^16, l^32 share a column)
#pragma unroll
    for (int fj = 0; fj < 8; ++fj) {
#pragma unroll
        for (int m = 16; m <= 32; m <<= 1) {
            float ov = __shfl_xor(bestv[fj], m);
            int   orr = __shfl_xor(bestr[fj], m);
            if (ov < bestv[fj] || (ov == bestv[fj] && orr < bestr[fj])) {
                bestv[fj] = ov; bestr[fj] = orr;
            }
        }
        if (lane < 16) {
            sRedV[wr * BN + colBase + fj * 16 + lane] = bestv[fj];
            sRedI[wr * BN + colBase + fj * 16 + lane] = bestr[fj];
        }
    }

#pragma unroll
    for (int off = 1; off < 64; off <<= 1) lsum += __shfl_xor(lsum, off);
    if (lane == 0) sWsum[w] = lsum;
    __syncthreads();

    if (tid < BN) {
        float bv = sRedV[tid];
        int   br = sRedI[tid];
#pragma unroll
        for (int q = 1; q < 4; ++q) {
            float v = sRedV[q * BN + tid];
            int   r = sRedI[q * BN + tid];
            if (v < bv || (v == bv && r < br)) { bv = v; br = r; }
        }
        out_assign[blk * BN + tid] = (float)br;
    }
    if (tid == 0) {
        float t = 0.f;
#pragma unroll
        for (int q = 0; q < 8; ++q) t += sWsum[q];
        partials[blk] = t;
    }
}

// ---------------------------------------------------------------------------
// Kernel 2: deterministic loss reduction over 256 block partials.
// ---------------------------------------------------------------------------
__global__ __launch_bounds__(256) void km_fin(const float* __restrict__ partials,
                                              float* __restrict__ out_loss) {
    __shared__ float ws[4];
    const int t = threadIdx.x;
    float v = partials[t];
#pragma unroll
    for (int off = 1; off < 64; off <<= 1) v += __shfl_xor(v, off);
    if ((t & 63) == 0) ws[t >> 6] = v;
    __syncthreads();
    if (t == 0) {
        float s = 0.f;
#pragma unroll
        for (int i = 0; i < 4; ++i) s += ws[i];
        out_loss[0] = s / 16777216.0f;   // mean over K*N
    }
}

extern "C" void kernel_launch(void* const* d_in, const int* in_sizes, int n_in,
                              void* d_out, int out_size, void* d_ws, size_t ws_size,
                              hipStream_t stream) {
    const float* x    = (const float*)d_in[0];
    const float* cent = (const float*)d_in[1];

    float* out        = (float*)d_out;
    float* out_dist   = out;                                  // [256][65536]
    float* out_assign = out + (size_t)K_CL * N_PTS;           // [65536] as float
    float* out_loss   = out_assign + N_PTS;                   // [1]

    char*   ws       = (char*)d_ws;
    float*  csq      = (float*)ws;                            // 256 f32
    float*  partials = (float*)(ws + 1024);                   // 256 f32
    ushort* Ahi      = (ushort*)(ws + 4096);                  // 512 KB
    ushort* Alo      = (ushort*)(ws + 4096 + 524288);         // 512 KB

    km_prep<<<dim3(K_CL), dim3(128), 0, stream>>>(cent, Ahi, Alo, csq);
    km_main<<<dim3(N_PTS / BN), dim3(THREADS), 0, stream>>>(
        x, Ahi, Alo, csq, out_dist, out_assign, partials);
    km_fin<<<dim3(1), dim3(256), 0, stream>>>(partials, out_loss);
}

// Round 6
// 117.749 us; speedup vs baseline: 1.0919x; 1.0919x over previous
//
#include <hip/hip_runtime.h>
#include <cstdint>

#define N_PTS 65536
#define DIM   1024
#define K_CL  256
#define BN    128
#define BK    32
#define NT    (DIM / BK)   // 32 k-tiles
#define THREADS 256

typedef __bf16 bf16_t;
typedef bf16_t bf16x8 __attribute__((ext_vector_type(8)));
typedef float  f32x4  __attribute__((ext_vector_type(4)));

union U16x8 { uint4 u4; bf16x8 bf; ushort us[8]; };

__device__ __forceinline__ ushort f2bf_rne(float f) {
    uint32_t u = __float_as_uint(f);
    uint32_t r = (u + 0x7FFFu + ((u >> 16) & 1u)) >> 16;
    return (ushort)r;
}
__device__ __forceinline__ float bf2f(ushort b) {
    return __uint_as_float(((uint32_t)b) << 16);
}

__device__ __forceinline__ void gll16(const void* g, void* l) {
    __builtin_amdgcn_global_load_lds(
        (const __attribute__((address_space(1))) void*)g,
        (__attribute__((address_space(3))) void*)l, 16, 0, 0);
}

#define BAR()   __builtin_amdgcn_s_barrier()
#define SCHB()  __builtin_amdgcn_sched_barrier(0)
#define LGKM0() do { asm volatile("s_waitcnt lgkmcnt(0)" ::: "memory"); \
                     __builtin_amdgcn_sched_barrier(0); } while (0)
#define VMCNT(N) do { asm volatile("s_waitcnt vmcnt(" #N ")" ::: "memory"); \
                      __builtin_amdgcn_sched_barrier(0); } while (0)
#define MFMA(ACC, A, B) (ACC) = __builtin_amdgcn_mfma_f32_16x16x32_bf16((A).bf, (B).bf, (ACC), 0, 0, 0)

// ---------------------------------------------------------------------------
// Kernel 0: centroids fp32 -> pre-swizzled bf16 hi/lo tile images + c_sq.
// ws layout per split: [NT tiles][256 rows][4 groups][8 bf16]; physical group
// slot gp holds d-group (gp ^ s), s = (row>>1)&3, so a LINEAR LDS copy of a
// tile gives bank-conflict-free swizzled reads (read slot g^s for d-group g).
// ---------------------------------------------------------------------------
__global__ __launch_bounds__(128) void km_prep(const float* __restrict__ cent,
                                               ushort* __restrict__ Ahi,
                                               ushort* __restrict__ Alo,
                                               float* __restrict__ csq) {
    const int r  = blockIdx.x;        // centroid row 0..255
    const int j  = threadIdx.x;       // 0..127
    const int kt = j >> 2;
    const int gp = j & 3;
    const int s  = (r >> 1) & 3;
    const int d0 = kt * BK + ((gp ^ s) << 3);

    const float* src = cent + r * DIM + d0;
    float4 a = *(const float4*)src;
    float4 b = *(const float4*)(src + 4);
    float v[8] = {a.x, a.y, a.z, a.w, b.x, b.y, b.z, b.w};

    U16x8 hi, lo;
    float ss = 0.f;
#pragma unroll
    for (int i = 0; i < 8; ++i) {
        float f = v[i];
        ss += f * f;
        ushort h = f2bf_rne(f);
        hi.us[i] = h;
        lo.us[i] = f2bf_rne(f - bf2f(h));
    }
    *(uint4*)(Ahi + kt * (K_CL * BK) + r * BK + gp * 8) = hi.u4;
    *(uint4*)(Alo + kt * (K_CL * BK) + r * BK + gp * 8) = lo.u4;

#pragma unroll
    for (int off = 1; off < 64; off <<= 1) ss += __shfl_xor(ss, off);
    __shared__ float ws2[2];
    if ((j & 63) == 0) ws2[j >> 6] = ss;
    __syncthreads();
    if (j == 0) csq[r] = ws2[0] + ws2[1];
}

// ---------------------------------------------------------------------------
// Kernel 1: fused distances + argmin + loss partial.
// Block = 256 thr (4 waves), tile 256 (all K) x 128 cols; wave = 64 x 128.
// LDS ~70 KB -> TWO blocks per CU: independent barrier domains overlap each
// other's stage/drain bubbles (m114 mechanism).  A-tile single-buffered
// (frags drained to regs via lgkmcnt(0) BEFORE the barrier that frees it);
// B double-buffered.  2 barriers per k-step, 96 MFMA/wave between them.
// Counted vmcnt(4): x-prefetch stays in flight across the barrier.
// gll16 dest MUST be uniform-base + lane*16 (m104): per-split chunks are
// tid*16 + {0,4096,8192,12288}.
// Split-bf16: hh + hl + lh.
// ---------------------------------------------------------------------------
__global__ __launch_bounds__(THREADS, 2) void km_main(
    const float* __restrict__ x,
    const ushort* __restrict__ Ahi, const ushort* __restrict__ Alo,
    const float* __restrict__ csq,
    float* __restrict__ out_dist, float* __restrict__ out_assign,
    float* __restrict__ partials) {

    __shared__ __align__(16) ushort sAhi[K_CL * BK];      // 16 KB (single buf)
    __shared__ __align__(16) ushort sAlo[K_CL * BK];      // 16 KB (single buf)
    __shared__ __align__(16) ushort sBhi[2][BN * BK];     // 16 KB
    __shared__ __align__(16) ushort sBlo[2][BN * BK];     // 16 KB
    __shared__ __align__(16) float  sCsq[K_CL];
    __shared__ __align__(16) float  sXsq[BN];
    __shared__ float sRedV[4 * BN];
    __shared__ int   sRedI[4 * BN];
    __shared__ float sWsum[4];

    const int tid  = threadIdx.x;
    const int blk  = blockIdx.x;
    const int lane = tid & 63;
    const int w    = tid >> 6;    // 0..3: wave owns rows w*64..w*64+63, all 128 cols
    const int l15  = lane & 15;
    const int l4   = lane >> 4;   // 0..3

    sCsq[tid] = csq[tid];         // 256 threads, 256 clusters

    // B staging: 2 threads per column, 16 d-elements each.
    const int bcol  = tid >> 1;                 // 0..127
    const int bhalf = tid & 1;                  // d-half: 0 -> d0..15, 1 -> d16..31
    const int bs    = (bcol >> 1) & 3;          // swizzle key
    const int bOff0 = bcol * BK + ((((bhalf << 1) | 0) ^ bs) << 3);
    const int bOff1 = bcol * BK + ((((bhalf << 1) | 1) ^ bs) << 3);
    const float* xsrc = x + (size_t)(blk * BN + bcol) * DIM + bhalf * 16;

    float xs_acc = 0.f;

    // A staging: 64 B per thread per split, as 4 chunks of (lane*16)-strided
    // gll16 at wave-uniform chunk offsets (HW semantics, m104).
    auto stageA = [&](int kt) {
        const char* ph = (const char*)Ahi + kt * 16384 + tid * 16;
        const char* pl = (const char*)Alo + kt * 16384 + tid * 16;
        char* dh = (char*)&sAhi[0] + tid * 16;
        char* dl = (char*)&sAlo[0] + tid * 16;
        gll16(ph,         dh);
        gll16(ph +  4096, dh +  4096);
        gll16(ph +  8192, dh +  8192);
        gll16(ph + 12288, dh + 12288);
        gll16(pl,         dl);
        gll16(pl +  4096, dl +  4096);
        gll16(pl +  8192, dl +  8192);
        gll16(pl + 12288, dl + 12288);
    };
    auto writeB = [&](int buf, float4 v0, float4 v1, float4 v2, float4 v3) {
        float f[16] = {v0.x, v0.y, v0.z, v0.w, v1.x, v1.y, v1.z, v1.w,
                       v2.x, v2.y, v2.z, v2.w, v3.x, v3.y, v3.z, v3.w};
        U16x8 h0, h1, l0, l1;
#pragma unroll
        for (int i = 0; i < 8; ++i) {
            float a = f[i];
            xs_acc = fmaf(a, a, xs_acc);
            bf16_t hb = (bf16_t)a;
            h0.bf[i] = hb;
            l0.bf[i] = (bf16_t)(a - (float)hb);
            float b = f[i + 8];
            xs_acc = fmaf(b, b, xs_acc);
            bf16_t hc = (bf16_t)b;
            h1.bf[i] = hc;
            l1.bf[i] = (bf16_t)(b - (float)hc);
        }
        *(uint4*)&sBhi[buf][bOff0] = h0.u4;
        *(uint4*)&sBhi[buf][bOff1] = h1.u4;
        *(uint4*)&sBlo[buf][bOff0] = l0.u4;
        *(uint4*)&sBlo[buf][bOff1] = l1.u4;
    };

    // fragment LDS offsets (ushort units), swizzle folded in
    int aOff[4], bOff[8];
#pragma unroll
    for (int f = 0; f < 4; ++f) {
        int row  = w * 64 + f * 16 + l15;
        aOff[f]  = row * BK + ((l4 ^ ((row >> 1) & 3)) << 3);
    }
#pragma unroll
    for (int f = 0; f < 8; ++f) {
        int col  = f * 16 + l15;
        bOff[f]  = col * BK + ((l4 ^ ((col >> 1) & 3)) << 3);
    }

    // prologue: stage tile 0, convert B(0), prefetch x(1)
    float4 b0, b1, b2, b3;
    stageA(0);
    b0 = *(const float4*)(xsrc);
    b1 = *(const float4*)(xsrc + 4);
    b2 = *(const float4*)(xsrc + 8);
    b3 = *(const float4*)(xsrc + 12);
    writeB(0, b0, b1, b2, b3);
    {
        const float* p = xsrc + BK;
        b0 = *(const float4*)p;
        b1 = *(const float4*)(p + 4);
        b2 = *(const float4*)(p + 8);
        b3 = *(const float4*)(p + 12);
    }
    __syncthreads();   // drains glls + ds_writes, full barrier (once)

    f32x4 acc[4][8];
#pragma unroll
    for (int i = 0; i < 4; ++i)
#pragma unroll
        for (int q = 0; q < 8; ++q) acc[i][q] = (f32x4){0.f, 0.f, 0.f, 0.f};

    for (int kt = 0; kt < NT; ++kt) {
        const int  cur = kt & 1, nxt = cur ^ 1;
        const bool pf1 = (kt + 1 < NT);
        const bool pf2 = (kt + 2 < NT);

        // ---- P1: drain A-frags into registers, then free sA ----
        U16x8 ah[4], al[4];
#pragma unroll
        for (int f = 0; f < 4; ++f) {
            ah[f].u4 = *(const uint4*)&sAhi[aOff[f]];
            al[f].u4 = *(const uint4*)&sAlo[aOff[f]];
        }
        LGKM0();                    // A-frags in regs; sA free to overwrite
        BAR();

        // ---- P2: stage A(kt+1) (oldest vmem), convert+write B(kt+1),
        //          prefetch x(kt+2), 96 MFMA streamed over fj ----
        if (pf1) stageA(kt + 1);    // 8 glls
        SCHB();                     // pin glls as the OLDEST vmem ops
        if (pf1) writeB(nxt, b0, b1, b2, b3);   // reads old b-regs (WAR pins loads below)
        if (pf2) {
            const float* p = xsrc + (kt + 2) * BK;
            b0 = *(const float4*)p;
            b1 = *(const float4*)(p + 4);
            b2 = *(const float4*)(p + 8);
            b3 = *(const float4*)(p + 12);
        }
        __builtin_amdgcn_s_setprio(1);
#pragma unroll
        for (int fj = 0; fj < 8; ++fj) {
            U16x8 bh, bl;
            bh.u4 = *(const uint4*)&sBhi[cur][bOff[fj]];
            bl.u4 = *(const uint4*)&sBlo[cur][bOff[fj]];
#pragma unroll
            for (int fi = 0; fi < 4; ++fi) MFMA(acc[fi][fj], ah[fi], bh);   // hh
#pragma unroll
            for (int fi = 0; fi < 4; ++fi) MFMA(acc[fi][fj], ah[fi], bl);   // hl
#pragma unroll
            for (int fi = 0; fi < 4; ++fi) MFMA(acc[fi][fj], al[fi], bh);   // lh
        }
        __builtin_amdgcn_s_setprio(0);
        if (pf2) { VMCNT(4); }      // glls done; 4 x-prefetch loads stay in flight
        else     { VMCNT(0); }      // tail: drain everything
        LGKM0();                    // own ds_writes (and fj reads) done
        BAR();                      // all waves: sA(kt+1) + sB[nxt] ready
    }

    // x_sq: 2 threads per column
    {
        float v = xs_acc;
        v += __shfl_xor(v, 1);
        if (bhalf == 0) sXsq[bcol] = v;
    }
    __syncthreads();

    // epilogue: distances, argmin, loss
    float xs[8];
    f32x4 cs[4];
#pragma unroll
    for (int f = 0; f < 8; ++f) xs[f] = sXsq[f * 16 + l15];
#pragma unroll
    for (int f = 0; f < 4; ++f) cs[f] = *(const f32x4*)&sCsq[w * 64 + f * 16 + l4 * 4];

    float lsum = 0.f;
    float bestv[8];
    int   bestr[8];
#pragma unroll
    for (int f = 0; f < 8; ++f) { bestv[f] = 3.4e38f; bestr[f] = 0; }

#pragma unroll
    for (int fi = 0; fi < 4; ++fi) {
        const int rowB = w * 64 + fi * 16 + l4 * 4;
#pragma unroll
        for (int fj = 0; fj < 8; ++fj) {
            const int col = blk * BN + fj * 16 + l15;
            float* outp = out_dist + (size_t)rowB * N_PTS + col;
#pragma unroll
            for (int j = 0; j < 4; ++j) {
                float d = cs[fi][j] + xs[fj] - 2.0f * acc[fi][fj][j];
                outp[(size_t)j * N_PTS] = d;
                lsum += d;
                int r = rowB + j;
                if (d < bestv[fj]) { bestv[fj] = d; bestr[fj] = r; }
            }
        }
    }

    // wave argmin over the wave's 64 rows (lanes l, l^16, l^32 share a column)
#pragma unroll
    for (int fj = 0; fj < 8; ++fj) {
#pragma unroll
        for (int m = 16; m <= 32; m <<= 1) {
            float ov = __shfl_xor(bestv[fj], m);
            int   orr = __shfl_xor(bestr[fj], m);
            if (ov < bestv[fj] || (ov == bestv[fj] && orr < bestr[fj])) {
                bestv[fj] = ov; bestr[fj] = orr;
            }
        }
        if (lane < 16) {
            sRedV[w * BN + fj * 16 + lane] = bestv[fj];
            sRedI[w * BN + fj * 16 + lane] = bestr[fj];
        }
    }

#pragma unroll
    for (int off = 1; off < 64; off <<= 1) lsum += __shfl_xor(lsum, off);
    if (lane == 0) sWsum[w] = lsum;
    __syncthreads();

    if (tid < BN) {
        float bv = sRedV[tid];
        int   br = sRedI[tid];
#pragma unroll
        for (int q = 1; q < 4; ++q) {
            float v = sRedV[q * BN + tid];
            int   r = sRedI[q * BN + tid];
            if (v < bv || (v == bv && r < br)) { bv = v; br = r; }
        }
        out_assign[blk * BN + tid] = (float)br;
    }
    if (tid == 0) {
        float t = 0.f;
#pragma unroll
        for (int q = 0; q < 4; ++q) t += sWsum[q];
        partials[blk] = t;
    }
}

// ---------------------------------------------------------------------------
// Kernel 2: deterministic loss reduction over 512 block partials.
// ---------------------------------------------------------------------------
__global__ __launch_bounds__(512) void km_fin(const float* __restrict__ partials,
                                              float* __restrict__ out_loss) {
    __shared__ float ws[8];
    const int t = threadIdx.x;
    float v = partials[t];
#pragma unroll
    for (int off = 1; off < 64; off <<= 1) v += __shfl_xor(v, off);
    if ((t & 63) == 0) ws[t >> 6] = v;
    __syncthreads();
    if (t == 0) {
        float s = 0.f;
#pragma unroll
        for (int i = 0; i < 8; ++i) s += ws[i];
        out_loss[0] = s / 16777216.0f;   // mean over K*N
    }
}

extern "C" void kernel_launch(void* const* d_in, const int* in_sizes, int n_in,
                              void* d_out, int out_size, void* d_ws, size_t ws_size,
                              hipStream_t stream) {
    const float* x    = (const float*)d_in[0];
    const float* cent = (const float*)d_in[1];

    float* out        = (float*)d_out;
    float* out_dist   = out;                                  // [256][65536]
    float* out_assign = out + (size_t)K_CL * N_PTS;           // [65536] as float
    float* out_loss   = out_assign + N_PTS;                   // [1]

    char*   ws       = (char*)d_ws;
    float*  csq      = (float*)ws;                            // 256 f32
    float*  partials = (float*)(ws + 1024);                   // 512 f32
    ushort* Ahi      = (ushort*)(ws + 4096);                  // 512 KB
    ushort* Alo      = (ushort*)(ws + 4096 + 524288);         // 512 KB

    km_prep<<<dim3(K_CL), dim3(128), 0, stream>>>(cent, Ahi, Alo, csq);
    km_main<<<dim3(N_PTS / BN), dim3(THREADS), 0, stream>>>(
        x, Ahi, Alo, csq, out_dist, out_assign, partials);
    km_fin<<<dim3(1), dim3(512), 0, stream>>>(partials, out_loss);
}